// Round 1
// 407.890 us; speedup vs baseline: 1.1079x; 1.1079x over previous
//
#include <hip/hip_runtime.h>
#include <stdint.h>

#define T_DIM   8192
#define IN_DIM  4096
#define OUT_DIM 4096
#define RANK    8

typedef int v4i __attribute__((ext_vector_type(4)));

__device__ __forceinline__ void async_copy16(const void* g, void* l) {
  __builtin_amdgcn_global_load_lds(
      (const __attribute__((address_space(1))) void*)g,
      (__attribute__((address_space(3))) void*)l, 16, 0, 0);
}

// ---------------------------------------------------------------------------
// prep: [0, 16384) pack weight int32 -> int8
//       [16384, 24576) per-row x quant + fp32 LoRA xa = x . A^T (8 dots)
// xa in fp32 (reference computes the LoRA path in fp32; this also deletes the
// old a_i8 quant, the atomic xa_i8 kernel, and the xa zero-fill).
// ---------------------------------------------------------------------------
#define PW_BLOCKS 16384
#define QX_BLOCKS 8192
#define PREP_BLOCKS (PW_BLOCKS + QX_BLOCKS)

__global__ __launch_bounds__(256) void prep(
    const int* __restrict__ w32,       // [OUT*IN] int32
    const float* __restrict__ x,       // [T, IN]
    const float* __restrict__ lora_a,  // [RANK, IN]
    int8_t* __restrict__ w8,           // [OUT*IN]
    int8_t* __restrict__ x_i8,         // [T, IN]
    float* __restrict__ x_scale,       // [T]
    float* __restrict__ xa)            // [T, RANK] fp32
{
  const int b = blockIdx.x;
  const int tid = threadIdx.x;
  __shared__ float red[4];
  __shared__ float redx[4][RANK];

  if (b < PW_BLOCKS) {
    const int idx = b * 256 + tid;
    const int4 v = ((const int4*)w32)[idx];
    char4 q;
    q.x = (signed char)v.x; q.y = (signed char)v.y;
    q.z = (signed char)v.z; q.w = (signed char)v.w;
    ((char4*)w8)[idx] = q;
    return;
  }

  const int row = b - PW_BLOCKS;
  const float4* xr = (const float4*)(x + (size_t)row * IN_DIM);
  float4 xv[4];
#pragma unroll
  for (int c = 0; c < 4; ++c) xv[c] = xr[c * 256 + tid];

  float am = 0.f;
#pragma unroll
  for (int c = 0; c < 4; ++c)
    am = fmaxf(am, fmaxf(fmaxf(fabsf(xv[c].x), fabsf(xv[c].y)),
                         fmaxf(fabsf(xv[c].z), fabsf(xv[c].w))));
#pragma unroll
  for (int off = 32; off > 0; off >>= 1)
    am = fmaxf(am, __shfl_xor(am, off, 64));
  if ((tid & 63) == 0) red[tid >> 6] = am;

  // fp32 LoRA dots: x row is already in registers; lora_a (128 KB) is L2-hot.
  float dot[RANK];
#pragma unroll
  for (int r = 0; r < RANK; ++r) {
    const float4* ar = (const float4*)(lora_a + (size_t)r * IN_DIM);
    float s = 0.f;
#pragma unroll
    for (int c = 0; c < 4; ++c) {
      const float4 a = ar[c * 256 + tid];
      s += xv[c].x * a.x + xv[c].y * a.y + xv[c].z * a.z + xv[c].w * a.w;
    }
    dot[r] = s;
  }
#pragma unroll
  for (int off = 32; off > 0; off >>= 1) {
#pragma unroll
    for (int r = 0; r < RANK; ++r)
      dot[r] += __shfl_xor(dot[r], off, 64);
  }
  if ((tid & 63) == 0) {
#pragma unroll
    for (int r = 0; r < RANK; ++r) redx[tid >> 6][r] = dot[r];
  }
  __syncthreads();

  const float amax = fmaxf(fmaxf(red[0], red[1]), fmaxf(red[2], red[3]));
  const float scale = amax * (1.0f / 127.0f);
  const float inv = 1.0f / fmaxf(scale, 1e-12f);
  char4* qout = (char4*)(x_i8 + (size_t)row * IN_DIM);
#pragma unroll
  for (int c = 0; c < 4; ++c) {
    char4 q;
    q.x = (signed char)(int)rintf(xv[c].x * inv);
    q.y = (signed char)(int)rintf(xv[c].y * inv);
    q.z = (signed char)(int)rintf(xv[c].z * inv);
    q.w = (signed char)(int)rintf(xv[c].w * inv);
    qout[c * 256 + tid] = q;
  }
  if (tid == 0) x_scale[row] = scale;
  if (tid < RANK)
    xa[(size_t)row * RANK + tid] =
        redx[0][tid] + redx[1][tid] + redx[2][tid] + redx[3][tid];
}

// ---------------------------------------------------------------------------
// GEMM: 256x256 tile, BK=64B, 512 thr (8 waves 2Mx4N, 128x64/wave),
// 3-buffer LDS (96 KiB) counted-vmcnt pipeline, XOR-swizzled LDS, setprio.
//
// Swizzle: logical (row, 16B-slot s) lives at LDS row*64 + (s ^ ((row>>1)&3))*16.
// global_load_lds writes LDS linearly (base + tid*16), so the swizzle is applied
// on the per-lane GLOBAL source address (inverse == forward, involution) and on
// the ds_read address. A wave's 64 fragment lanes then hit 64 distinct 16B
// units -> uniform bank load (was 8-way conflict).
//
// Pipeline invariants (race-freedom):
//  - tile t lives in buf t%3; stage of tile t+2 at iter t targets buf (t-1)%3,
//    whose reads finished at iter t-1, strictly before iter t's barrier.
//  - per-iter wait is vmcnt(4): tile t's 4 loads landed, tile t+1's 4 stay in
//    flight across the barrier (no drain-to-0 in the steady state).
// ---------------------------------------------------------------------------
#define SYNC(n) do {                                      \
    asm volatile("s_waitcnt vmcnt(" #n ")" ::: "memory"); \
    __builtin_amdgcn_s_barrier();                         \
    __builtin_amdgcn_sched_barrier(0);                    \
  } while (0)

__device__ __forceinline__ void stage_tile(const int8_t* aSrc, const int8_t* bSrc,
                                           int8_t* Lbuf, int ldsOff) {
  async_copy16(aSrc,                          Lbuf + ldsOff);
  async_copy16(aSrc + (size_t)128 * IN_DIM,   Lbuf + 8192 + ldsOff);
  async_copy16(bSrc,                          Lbuf + 16384 + ldsOff);
  async_copy16(bSrc + (size_t)128 * IN_DIM,   Lbuf + 16384 + 8192 + ldsOff);
}

__device__ __forceinline__ void compute_tile(const int8_t* Lbuf, int aOff, int bOff,
                                             v4i (&acc)[8][4]) {
  const int8_t* La = Lbuf;
  const int8_t* Lb = Lbuf + 16384;
  v4i aF[8], bF[4];
#pragma unroll
  for (int i = 0; i < 8; ++i) aF[i] = *(const v4i*)(La + aOff + i * 1024);
#pragma unroll
  for (int j = 0; j < 4; ++j) bF[j] = *(const v4i*)(Lb + bOff + j * 1024);
  __builtin_amdgcn_s_setprio(1);
#pragma unroll
  for (int i = 0; i < 8; ++i)
#pragma unroll
    for (int j = 0; j < 4; ++j)
      acc[i][j] = __builtin_amdgcn_mfma_i32_16x16x64_i8(aF[i], bF[j], acc[i][j], 0, 0, 0);
  __builtin_amdgcn_s_setprio(0);
}

__global__ __launch_bounds__(512, 2) void gemm256_i8(
    const int8_t* __restrict__ A,       // x_i8 [T, IN]
    const int8_t* __restrict__ B,       // w8 [OUT, IN]
    const float* __restrict__ x_scale,  // [T]
    const float* __restrict__ w_scale,  // [OUT]
    const float* __restrict__ xa,       // [T, RANK] fp32
    const float* __restrict__ lora_b,   // [OUT, RANK]
    float* __restrict__ out)            // [T, OUT]
{
  __shared__ __align__(16) int8_t smem[3 * 32768];  // 96 KiB: [buf][A 16K | B 16K]
  const int tid = threadIdx.x;

  // XCD-bijective swizzle (512 blocks % 8 == 0): each XCD gets 64 consecutive
  // wgids = 4 contiguous A-panels (4 MB, L2-resident) x all 16 B-panels.
  const int orig = blockIdx.x;
  const int wgid = ((orig & 7) << 6) | (orig >> 3);
  const int by = wgid >> 4;   // 0..31
  const int bx = wgid & 15;   // 0..15
  const size_t arow0 = (size_t)by * 256;
  const size_t brow0 = (size_t)bx * 256;

  // staging addressing: thread tid covers (row = tid>>2 [+128], slot = tid&3);
  // source slot pre-swizzled so linear LDS write realizes the swizzled layout.
  const int r_l = tid >> 2;
  const int qsw = ((tid & 3) ^ ((r_l >> 1) & 3)) << 4;
  const int8_t* aSrc = A + (arow0 + r_l) * IN_DIM + qsw;
  const int8_t* bSrc = B + (brow0 + r_l) * IN_DIM + qsw;
  const int ldsOff = tid << 4;

  const int lane = tid & 63;
  const int wave = tid >> 6;
  const int wr = wave >> 2, wc = wave & 3;       // 2 x 4 wave grid
  const int m16 = lane & 15, quad = lane >> 4;
  const int sw = (quad ^ ((m16 >> 1) & 3)) << 4; // read-side swizzle
  const int aOff = (wr * 128 + m16) * 64 + sw;   // + i*1024
  const int bOff = (wc * 64 + m16) * 64 + sw;    // + j*1024

  v4i acc[8][4];
  const v4i vz = {0, 0, 0, 0};
#pragma unroll
  for (int i = 0; i < 8; ++i)
#pragma unroll
    for (int j = 0; j < 4; ++j) acc[i][j] = vz;

  // prologue: tiles 0,1 in flight (8 loads)
  stage_tile(aSrc, bSrc, smem, ldsOff);
  stage_tile(aSrc + 64, bSrc + 64, smem + 32768, ldsOff);

#pragma unroll 1
  for (int t = 0; t < 60; t += 3) {
    SYNC(4);
    stage_tile(aSrc + (t + 2) * 64, bSrc + (t + 2) * 64, smem + 2 * 32768, ldsOff);
    compute_tile(smem, aOff, bOff, acc);                       // tile t   (buf0)
    SYNC(4);
    stage_tile(aSrc + (t + 3) * 64, bSrc + (t + 3) * 64, smem, ldsOff);
    compute_tile(smem + 32768, aOff, bOff, acc);               // tile t+1 (buf1)
    SYNC(4);
    stage_tile(aSrc + (t + 4) * 64, bSrc + (t + 4) * 64, smem + 32768, ldsOff);
    compute_tile(smem + 2 * 32768, aOff, bOff, acc);           // tile t+2 (buf2)
  }
  SYNC(4);
  stage_tile(aSrc + 62 * 64, bSrc + 62 * 64, smem + 2 * 32768, ldsOff);
  compute_tile(smem, aOff, bOff, acc);                         // tile 60 (buf0)
  SYNC(4);
  stage_tile(aSrc + 63 * 64, bSrc + 63 * 64, smem, ldsOff);
  compute_tile(smem + 32768, aOff, bOff, acc);                 // tile 61 (buf1)
  SYNC(4);
  compute_tile(smem + 2 * 32768, aOff, bOff, acc);             // tile 62 (buf2)
  asm volatile("s_waitcnt vmcnt(0)" ::: "memory");
  __builtin_amdgcn_s_barrier();
  __builtin_amdgcn_sched_barrier(0);
  compute_tile(smem, aOff, bOff, acc);                         // tile 63 (buf0)

  // ---------------- epilogue: dequant + LoRA add ----------------
  __syncthreads();                     // all LDS reads done; reuse smem
  float* fs   = (float*)smem;
  float* xs_s = fs;                    // 256
  float* ws_s = fs + 256;              // 256
  float* xa_s = fs + 512;              // 256*8
  float* lb_s = fs + 2560;             // 256*8
  if (tid < 256) xs_s[tid] = x_scale[arow0 + tid];
  else           ws_s[tid - 256] = w_scale[brow0 + (tid - 256)];
  ((float4*)xa_s)[tid] = ((const float4*)(xa + arow0 * RANK))[tid];
  ((float4*)lb_s)[tid] = ((const float4*)(lora_b + brow0 * RANK))[tid];
  __syncthreads();

  float wscv[4];
  float4 lb0[4], lb1[4];
  int cols[4];
#pragma unroll
  for (int j = 0; j < 4; ++j) {
    const int c = wc * 64 + j * 16 + m16;
    cols[j] = c;
    wscv[j] = ws_s[c];
    lb0[j] = *(const float4*)(lb_s + c * RANK);
    lb1[j] = *(const float4*)(lb_s + c * RANK + 4);
  }
#pragma unroll
  for (int i = 0; i < 8; ++i) {
#pragma unroll
    for (int reg = 0; reg < 4; ++reg) {
      const int r = wr * 128 + i * 16 + quad * 4 + reg;   // C/D row map (verified)
      const float xsc = xs_s[r];
      const float4 xa0 = *(const float4*)(xa_s + r * RANK);
      const float4 xa1 = *(const float4*)(xa_s + r * RANK + 4);
      float* orow = out + (arow0 + (size_t)r) * OUT_DIM + brow0;
#pragma unroll
      for (int j = 0; j < 4; ++j) {
        float v = (float)acc[i][j][reg] * xsc * wscv[j];
        v += xa0.x * lb0[j].x + xa0.y * lb0[j].y + xa0.z * lb0[j].z + xa0.w * lb0[j].w +
             xa1.x * lb1[j].x + xa1.y * lb1[j].y + xa1.z * lb1[j].z + xa1.w * lb1[j].w;
        orow[cols[j]] = v;
      }
    }
  }
}

// ---------------------------------------------------------------------------
extern "C" void kernel_launch(void* const* d_in, const int* in_sizes, int n_in,
                              void* d_out, int out_size, void* d_ws, size_t ws_size,
                              hipStream_t stream) {
  const float* x       = (const float*)d_in[0];
  const int*   w_i32   = (const int*)d_in[1];    // integer inputs upload as int32
  const float* w_scale = (const float*)d_in[2];
  const float* lora_a  = (const float*)d_in[3];
  const float* lora_b  = (const float*)d_in[4];
  float* out = (float*)d_out;

  // ws: x_i8 | w8 | x_scale[T] | xa[T][RANK]
  int8_t* x_i8    = (int8_t*)d_ws;
  int8_t* w8      = x_i8 + (size_t)T_DIM * IN_DIM;
  float*  x_scale = (float*)(w8 + (size_t)OUT_DIM * IN_DIM);
  float*  xa      = x_scale + T_DIM;

  prep<<<PREP_BLOCKS, 256, 0, stream>>>(w_i32, x, lora_a, w8, x_i8, x_scale, xa);
  gemm256_i8<<<(T_DIM / 256) * (OUT_DIM / 256), 512, 0, stream>>>(
      x_i8, w8, x_scale, w_scale, xa, lora_b, out);
}